// Round 1
// baseline (3694.848 us; speedup 1.0000x reference)
//
#include <hip/hip_runtime.h>
#include <hip/hip_bf16.h>

#define TT 512
#define BB 128
#define II 256
#define HH 512
#define OO 256

#define NGB 8     // batch groups
#define NGN 16    // N-slices per group
#define RB  16    // batch rows per group
#define NS  32    // hidden cols per slice

#define PRED_SZ (TT*OO)

typedef __attribute__((ext_vector_type(8))) short bf16x8;
typedef __attribute__((ext_vector_type(4))) float f32x4;

// workspace layout (bytes)
#define WS_CNT  0                          // (TT+1)*NGB ints = 16416 B
#define WS_H1   16512                      // [2][BB][HH] bf16 = 262144 B
#define WS_H2   (WS_H1 + 2*BB*HH*2)        // [2][BB][HH] bf16
#define WS_SAVE (WS_H2 + 2*BB*HH*2)        // [TT][HH] f32 = 1 MB
#define WS_ZERO WS_SAVE                    // zero cnt + both h buffers each launch

__device__ __forceinline__ ushort f2bf(float f) {
  union { float f; unsigned u; } v; v.f = f;
  unsigned u = v.u;
  return (ushort)((u + 0x7FFFu + ((u >> 16) & 1u)) >> 16);   // RNE
}

__global__ __launch_bounds__(256) void rnn_scan_kernel(
    const float* __restrict__ x,
    const float* __restrict__ Wih0, const float* __restrict__ bih0,
    const float* __restrict__ Whh0, const float* __restrict__ bhh0,
    const float* __restrict__ Wih1, const float* __restrict__ bih1,
    const float* __restrict__ Whh1, const float* __restrict__ bhh1,
    float* __restrict__ out, char* __restrict__ ws)
{
  // packed B-fragments: unit u (0..111) = {Wih0: 0..15, Whh0: 16..47, Wih1: 48..79, Whh1: 80..111}
  // layout: ldsW[(u*64 + lane)*8 + j] = W[n0 + tile*16 + (lane&15)][kk*32 + (lane>>4)*8 + j]
  __shared__ ushort ldsW[112*64*8];        // 112 KiB
  __shared__ float bias0[NS];
  __shared__ float bias1[NS];

  int*    cnt    = (int*)(ws + WS_CNT);
  ushort* h1buf  = (ushort*)(ws + WS_H1);
  ushort* h2buf  = (ushort*)(ws + WS_H2);
  float*  h2save = (float*)(ws + WS_SAVE);

  const int tid = threadIdx.x;
  const int gb  = blockIdx.x & 7;          // batch group (also XCD-locality heuristic)
  const int gn  = blockIdx.x >> 3;         // N-slice
  const int n0  = gn * NS;

  // ---- one-time: pack weight slices (fp32 global -> bf16 LDS, fragment order) ----
  {
    const int lane = tid & 63;
    const int q    = tid >> 6;             // j-pair q*2, q*2+1
    #pragma unroll 1
    for (int u = 0; u < 112; ++u) {
      const float* Wsrc; int Km; int ul;
      if (u < 16)      { Wsrc = Wih0; Km = II; ul = u; }
      else if (u < 48) { Wsrc = Whh0; Km = HH; ul = u - 16; }
      else if (u < 80) { Wsrc = Wih1; Km = HH; ul = u - 48; }
      else             { Wsrc = Whh1; Km = HH; ul = u - 80; }
      const int nk  = Km >> 5;             // k-steps for this matrix
      const int ttl = ul / nk;
      const int kk  = ul - ttl*nk;
      const int n   = n0 + ttl*16 + (lane & 15);
      const int k   = kk*32 + (lane >> 4)*8 + q*2;
      const float2 wv = *(const float2*)(Wsrc + (size_t)n*Km + k);
      ushort2 b2; b2.x = f2bf(wv.x); b2.y = f2bf(wv.y);
      *(ushort2*)&ldsW[(u*64 + lane)*8 + q*2] = b2;
    }
    if (tid < NS) {
      bias0[tid] = bih0[n0+tid] + bhh0[n0+tid];
      bias1[tid] = bih1[n0+tid] + bhh1[n0+tid];
    }
  }
  __syncthreads();

  const int w     = tid >> 6;              // wave 0..3
  const int lane  = tid & 63;
  const int ttile = w & 1;                 // which 16-col tile of the 32-col slice
  const int layer = w >> 1;                // waves 0,1 -> layer0; 2,3 -> layer1
  const int kq    = lane >> 4;
  const int rowg  = gb*RB + (lane & 15);   // batch row this lane loads A-fragments for
  const int c     = lane & 15;             // C/D column within tile

  for (int p = 0; p <= TT; ++p) {
    // x prefetch for layer0 — independent of the sync, issued before the poll
    f32x4 xf[16];
    if (layer == 0 && p < TT) {
      const float* xp = x + ((size_t)p*BB + rowg)*II + kq*8;
      #pragma unroll
      for (int kk = 0; kk < 8; ++kk) {
        xf[2*kk]   = *(const f32x4*)(xp + kk*32);
        xf[2*kk+1] = *(const f32x4*)(xp + kk*32 + 4);
      }
    }
    // wait for all 16 slices of this batch group from phase p-1
    if (p > 0) {
      if (tid == 0) {
        while (__hip_atomic_load(&cnt[(p-1)*NGB + gb], __ATOMIC_ACQUIRE,
                                 __HIP_MEMORY_SCOPE_AGENT) < NGN) {
          __builtin_amdgcn_s_sleep(1);
        }
      }
      __syncthreads();
    }

    if (layer == 0) {
      if (p < TT) {
        // h1[p] = tanh( x[p] @ Wih0^T + h1[p-1] @ Whh0^T + b )
        bf16x8 af[16];
        const ushort* ap = h1buf + ((size_t)((p-1)&1)*BB + rowg)*HH + kq*8;
        #pragma unroll
        for (int kk = 0; kk < 16; ++kk) af[kk] = *(const bf16x8*)(ap + kk*32);
        f32x4 acc = {0.f,0.f,0.f,0.f};
        #pragma unroll
        for (int kk = 0; kk < 8; ++kk) {
          bf16x8 a;
          #pragma unroll
          for (int j = 0; j < 4; ++j) {
            a[j]   = (short)f2bf(xf[2*kk][j]);
            a[j+4] = (short)f2bf(xf[2*kk+1][j]);
          }
          const bf16x8 b = *(const bf16x8*)&ldsW[((0 + ttile*8 + kk)*64 + lane)*8];
          acc = __builtin_amdgcn_mfma_f32_16x16x32_bf16(a, b, acc, 0, 0, 0);
        }
        #pragma unroll
        for (int kk = 0; kk < 16; ++kk) {
          const bf16x8 b = *(const bf16x8*)&ldsW[((16 + ttile*16 + kk)*64 + lane)*8];
          acc = __builtin_amdgcn_mfma_f32_16x16x32_bf16(af[kk], b, acc, 0, 0, 0);
        }
        const float bv = bias0[ttile*16 + c];
        ushort* dst = h1buf + (size_t)(p&1)*BB*HH;
        const int col = n0 + ttile*16 + c;
        #pragma unroll
        for (int j = 0; j < 4; ++j) {
          const int r = gb*16 + kq*4 + j;
          const float v = tanhf(acc[j] + bv);
          dst[(size_t)r*HH + col] = f2bf(v);
          if (p == TT-1) out[PRED_SZ + (size_t)r*HH + col] = v;   // h_final[0]
        }
      }
    } else {
      if (p >= 1) {
        // h2[p-1] = tanh( h1[p-1] @ Wih1^T + h2[p-2] @ Whh1^T + b )
        bf16x8 af[16], a2[16];
        const ushort* ap  = h1buf + ((size_t)((p-1)&1)*BB + rowg)*HH + kq*8;
        const ushort* a2p = h2buf + ((size_t)(p&1)*BB + rowg)*HH + kq*8;  // (p-2)&1 == p&1
        #pragma unroll
        for (int kk = 0; kk < 16; ++kk) {
          af[kk] = *(const bf16x8*)(ap  + kk*32);
          a2[kk] = *(const bf16x8*)(a2p + kk*32);
        }
        f32x4 acc = {0.f,0.f,0.f,0.f};
        #pragma unroll
        for (int kk = 0; kk < 16; ++kk) {
          const bf16x8 b = *(const bf16x8*)&ldsW[((48 + ttile*16 + kk)*64 + lane)*8];
          acc = __builtin_amdgcn_mfma_f32_16x16x32_bf16(af[kk], b, acc, 0, 0, 0);
        }
        #pragma unroll
        for (int kk = 0; kk < 16; ++kk) {
          const bf16x8 b = *(const bf16x8*)&ldsW[((80 + ttile*16 + kk)*64 + lane)*8];
          acc = __builtin_amdgcn_mfma_f32_16x16x32_bf16(a2[kk], b, acc, 0, 0, 0);
        }
        const float bv = bias1[ttile*16 + c];
        ushort* dst = h2buf + (size_t)((p-1)&1)*BB*HH;
        const int col = n0 + ttile*16 + c;
        #pragma unroll
        for (int j = 0; j < 4; ++j) {
          const int r = gb*16 + kq*4 + j;
          const float v = tanhf(acc[j] + bv);
          dst[(size_t)r*HH + col] = f2bf(v);
          if (r == BB-1) h2save[(size_t)(p-1)*HH + col] = v;       // trajectory of batch row 127
          if (p == TT) out[PRED_SZ + BB*HH + (size_t)r*HH + col] = v;  // h_final[1]
        }
      }
    }

    __syncthreads();   // all waves' slice writes done
    if (tid == 0) {
      __hip_atomic_fetch_add(&cnt[p*NGB + gb], 1, __ATOMIC_RELEASE,
                             __HIP_MEMORY_SCOPE_AGENT);
    }
  }
}

__global__ __launch_bounds__(256) void rnn_pred_kernel(
    const float* __restrict__ Wfc, const float* __restrict__ bfc,
    const float* __restrict__ h2save, float* __restrict__ out)
{
  __shared__ float hs[HH];
  const int t = blockIdx.x;
  for (int i = threadIdx.x; i < HH; i += 256) hs[i] = h2save[(size_t)t*HH + i];
  __syncthreads();
  const int o = threadIdx.x;
  const f32x4* wr = (const f32x4*)(Wfc + (size_t)o*HH);
  f32x4 s = {0.f,0.f,0.f,0.f};
  #pragma unroll 8
  for (int k = 0; k < HH/4; ++k) {
    const f32x4 wv = wr[k];
    const f32x4 hv = *(const f32x4*)&hs[4*k];
    s += wv * hv;
  }
  out[(size_t)t*OO + o] = bfc[o] + s[0] + s[1] + s[2] + s[3];
}

extern "C" void kernel_launch(void* const* d_in, const int* in_sizes, int n_in,
                              void* d_out, int out_size, void* d_ws, size_t ws_size,
                              hipStream_t stream) {
  const float* x    = (const float*)d_in[0];
  const float* Wih0 = (const float*)d_in[1];
  const float* bih0 = (const float*)d_in[2];
  const float* Whh0 = (const float*)d_in[3];
  const float* bhh0 = (const float*)d_in[4];
  const float* Wih1 = (const float*)d_in[5];
  const float* bih1 = (const float*)d_in[6];
  const float* Whh1 = (const float*)d_in[7];
  const float* bhh1 = (const float*)d_in[8];
  const float* Wfc  = (const float*)d_in[9];
  const float* bfc  = (const float*)d_in[10];
  float* out = (float*)d_out;
  char*  ws  = (char*)d_ws;

  // zero sync counters + both parities of h1/h2 ping-pong buffers (h[-1]=0, h[-2]=0)
  hipMemsetAsync(ws, 0, WS_ZERO, stream);

  rnn_scan_kernel<<<NGB*NGN, 256, 0, stream>>>(x, Wih0, bih0, Whh0, bhh0,
                                               Wih1, bih1, Whh1, bhh1, out, ws);
  rnn_pred_kernel<<<TT, 256, 0, stream>>>(Wfc, bfc, (const float*)(ws + WS_SAVE), out);
}